// Round 8
// baseline (632.060 us; speedup 1.0000x reference)
//
#include <hip/hip_runtime.h>

// Problem constants (B=4, T=8, N=2048, C=64)
#define BB 4
#define TT 8
#define NN 2048
#define CC 64
#define MM 512           // N / SPATIAL_STRIDE
#define KK 32
#define H3DIM 256
#define RAD2 0.25f
#define FINF 3.4e38f

typedef _Float16 f16x8 __attribute__((ext_vector_type(8)));
typedef _Float16 f16x4 __attribute__((ext_vector_type(4)));
typedef float f32x4 __attribute__((ext_vector_type(4)));

// ---------------------------------------------------------------------------
// Packed-key DPP wave-64 reduces. Key = (float_bits << 32) | payload.
// Non-negative floats compare correctly as unsigned bits.
// Pattern (row_shr 1/2/4/8 + row_bcast15/31, result in lane 63) HW-validated
// by k_fps in rounds 2-5.
// ---------------------------------------------------------------------------
template <int CTRL>
__device__ __forceinline__ unsigned long long dpp_maxkey_step(unsigned long long k) {
    int lo = (int)(unsigned)k;
    int hi = (int)(unsigned)(k >> 32);
    int slo = __builtin_amdgcn_update_dpp(lo, lo, CTRL, 0xf, 0xf, false);
    int shi = __builtin_amdgcn_update_dpp(hi, hi, CTRL, 0xf, 0xf, false);
    unsigned long long s = ((unsigned long long)(unsigned)shi << 32) | (unsigned)slo;
    return s > k ? s : k;
}
template <int CTRL>
__device__ __forceinline__ unsigned long long dpp_minkey_step(unsigned long long k) {
    int lo = (int)(unsigned)k;
    int hi = (int)(unsigned)(k >> 32);
    int slo = __builtin_amdgcn_update_dpp(lo, lo, CTRL, 0xf, 0xf, false);
    int shi = __builtin_amdgcn_update_dpp(hi, hi, CTRL, 0xf, 0xf, false);
    unsigned long long s = ((unsigned long long)(unsigned)shi << 32) | (unsigned)slo;
    return s < k ? s : k;
}
__device__ __forceinline__ unsigned long long wave_maxkey(unsigned long long k) {
    k = dpp_maxkey_step<0x111>(k);
    k = dpp_maxkey_step<0x112>(k);
    k = dpp_maxkey_step<0x114>(k);
    k = dpp_maxkey_step<0x118>(k);
    k = dpp_maxkey_step<0x142>(k);
    k = dpp_maxkey_step<0x143>(k);
    int lo = __builtin_amdgcn_readlane((int)(unsigned)k, 63);
    int hi = __builtin_amdgcn_readlane((int)(unsigned)(k >> 32), 63);
    return ((unsigned long long)(unsigned)hi << 32) | (unsigned)lo;
}
__device__ __forceinline__ unsigned long long wave_minkey(unsigned long long k) {
    k = dpp_minkey_step<0x111>(k);
    k = dpp_minkey_step<0x112>(k);
    k = dpp_minkey_step<0x114>(k);
    k = dpp_minkey_step<0x118>(k);
    k = dpp_minkey_step<0x142>(k);
    k = dpp_minkey_step<0x143>(k);
    int lo = __builtin_amdgcn_readlane((int)(unsigned)k, 63);
    int hi = __builtin_amdgcn_readlane((int)(unsigned)(k >> 32), 63);
    return ((unsigned long long)(unsigned)hi << 32) | (unsigned)lo;
}

// ---------------------------------------------------------------------------
// Kernel 1: farthest point sampling. 4 waves (256 thr) per (b,t) cloud.
// Per-iter: lane scan -> u64-key DPP max -> winner lane writes {key,x,y,z}
// record to LDS -> barrier -> all threads 4-record key tree -> next cur coords
// directly (no second LDS round-trip). Tie-break = smallest index, exact.
// ---------------------------------------------------------------------------
__global__ __launch_bounds__(256) void k_fps(const float* __restrict__ xyzs,
                                             int* __restrict__ fps_idx) {
    int bt = blockIdx.x;
    int tid = threadIdx.x;
    int w = tid >> 6;
    __shared__ float sx[NN], sy[NN], sz[NN];
    __shared__ int recs[2][4][8];          // [buf][wave][keyhi,keylo,x,y,z,pad]
    const float* src = xyzs + (size_t)bt * NN * 3;
    for (int i = tid; i < NN; i += 256) {
        sx[i] = src[i * 3 + 0];
        sy[i] = src[i * 3 + 1];
        sz[i] = src[i * 3 + 2];
    }
    __syncthreads();

    float px[8], py[8], pz[8], dist[8];
#pragma unroll
    for (int j = 0; j < 8; ++j) {
        int p = tid * 8 + j;
        px[j] = sx[p]; py[j] = sy[p]; pz[j] = sz[p];
        dist[j] = 1e10f;
    }

    if (tid == 0) fps_idx[bt * MM + 0] = 0;
    int pbase = tid * 8;
    float cx = sx[0], cy = sy[0], cz = sz[0];

    for (int it = 1; it < MM; ++it) {
        float bestd = -1.0f;
        int bestp = 0;
#pragma unroll
        for (int j = 0; j < 8; ++j) {
            float dx = px[j] - cx, dy = py[j] - cy, dz = pz[j] - cz;
            float d = dx * dx + dy * dy + dz * dz;
            float nd = fminf(dist[j], d);
            dist[j] = nd;
            if (nd > bestd) { bestd = nd; bestp = pbase + j; }  // strict > keeps smallest j
        }
        // key: max d, tie -> smallest p (via ~p in low bits)
        unsigned long long mykey =
            ((unsigned long long)(unsigned)__builtin_bit_cast(unsigned, bestd) << 32) |
            (unsigned)(~(unsigned)bestp);
        unsigned long long wkey = wave_maxkey(mykey);
        if (mykey == wkey) {               // unique winner lane in wave
            int j3 = bestp & 7;
            bool b0 = (j3 & 1) != 0, b1 = (j3 & 2) != 0, b2 = (j3 & 4) != 0;
            float x01 = b0 ? px[1] : px[0], x23 = b0 ? px[3] : px[2];
            float x45 = b0 ? px[5] : px[4], x67 = b0 ? px[7] : px[6];
            float y01 = b0 ? py[1] : py[0], y23 = b0 ? py[3] : py[2];
            float y45 = b0 ? py[5] : py[4], y67 = b0 ? py[7] : py[6];
            float z01 = b0 ? pz[1] : pz[0], z23 = b0 ? pz[3] : pz[2];
            float z45 = b0 ? pz[5] : pz[4], z67 = b0 ? pz[7] : pz[6];
            float x0123 = b1 ? x23 : x01, x4567 = b1 ? x67 : x45;
            float y0123 = b1 ? y23 : y01, y4567 = b1 ? y67 : y45;
            float z0123 = b1 ? z23 : z01, z4567 = b1 ? z67 : z45;
            float wx = b2 ? x4567 : x0123;
            float wy = b2 ? y4567 : y0123;
            float wz = b2 ? z4567 : z0123;
            int* rec = &recs[it & 1][w][0];
            rec[0] = (int)(unsigned)(wkey >> 32);
            rec[1] = (int)(unsigned)wkey;
            rec[2] = __builtin_bit_cast(int, wx);
            rec[3] = __builtin_bit_cast(int, wy);
            rec[4] = __builtin_bit_cast(int, wz);
        }
        __syncthreads();
        // combine 4 wave records (broadcast reads, key tree)
        int4 r0 = *(const int4*)&recs[it & 1][0][0];
        float z0 = __builtin_bit_cast(float, recs[it & 1][0][4]);
        int4 r1 = *(const int4*)&recs[it & 1][1][0];
        float z1 = __builtin_bit_cast(float, recs[it & 1][1][4]);
        int4 r2 = *(const int4*)&recs[it & 1][2][0];
        float z2 = __builtin_bit_cast(float, recs[it & 1][2][4]);
        int4 r3 = *(const int4*)&recs[it & 1][3][0];
        float z3 = __builtin_bit_cast(float, recs[it & 1][3][4]);
        unsigned long long k0 = ((unsigned long long)(unsigned)r0.x << 32) | (unsigned)r0.y;
        unsigned long long k1 = ((unsigned long long)(unsigned)r1.x << 32) | (unsigned)r1.y;
        unsigned long long k2 = ((unsigned long long)(unsigned)r2.x << 32) | (unsigned)r2.y;
        unsigned long long k3 = ((unsigned long long)(unsigned)r3.x << 32) | (unsigned)r3.y;
        bool t01 = k1 > k0, t23 = k3 > k2;
        unsigned long long ka = t01 ? k1 : k0, kb = t23 ? k3 : k2;
        float xa = __builtin_bit_cast(float, t01 ? r1.z : r0.z);
        float ya = __builtin_bit_cast(float, t01 ? r1.w : r0.w);
        float za = t01 ? z1 : z0;
        float xb = __builtin_bit_cast(float, t23 ? r3.z : r2.z);
        float yb = __builtin_bit_cast(float, t23 ? r3.w : r2.w);
        float zb = t23 ? z3 : z2;
        bool tf = kb > ka;
        unsigned long long kf = tf ? kb : ka;
        cx = tf ? xb : xa;
        cy = tf ? yb : ya;
        cz = tf ? zb : za;
        if (tid == 0) fps_idx[bt * MM + it] = (int)(~(unsigned)kf);
    }
}

// ---------------------------------------------------------------------------
// Kernel 2a: P'[row,c] (fp16) = feat_n.W1[0:64] + xyz_n.W1[128:131]
// (unchanged — verified)
// ---------------------------------------------------------------------------
__global__ __launch_bounds__(256) void k_pp(const float* __restrict__ xyzs,
                                            const float* __restrict__ feats,
                                            const float* __restrict__ w1,
                                            _Float16* __restrict__ Pp) {
    __shared__ float sw[68 * 128];
    __shared__ float sin_[64 * 68];
    int tid = threadIdx.x;
    for (int i = tid; i < 68 * 128; i += 256) {
        int r = i >> 7, c = i & 127;
        float v = 0.f;
        if (r < 64) v = w1[r * 128 + c];
        else if (r < 67) v = w1[(128 + r - 64) * 128 + c];
        sw[i] = v;
    }
    int row0 = blockIdx.x * 64;
    int bt = row0 >> 11;
    int b = bt >> 3, t = bt & 7;
    int tn = (t + 1 < TT) ? (t + 1) : (TT - 1);
    size_t nbase = (size_t)(b * TT + tn) * NN + (row0 & (NN - 1));
    const float* fsrc = feats + nbase * CC;
    const float* xsrc = xyzs + nbase * 3;
    for (int i = tid; i < 1024; i += 256) {
        float4 v = ((const float4*)fsrc)[i];
        int r = i >> 4, c = (i & 15) * 4;
        *(float4*)&sin_[r * 68 + c] = v;
    }
    if (tid < 192) {
        int r = tid / 3, c = tid - r * 3;
        sin_[r * 68 + 64 + c] = xsrc[tid];
    }
    if (tid < 64) sin_[tid * 68 + 67] = 0.f;
    __syncthreads();

    int rowg = tid >> 5, colg = tid & 31;
    float4 acc[8];
#pragma unroll
    for (int i = 0; i < 8; ++i) acc[i] = make_float4(0.f, 0.f, 0.f, 0.f);
    for (int k = 0; k < 68; k += 4) {
        float4 a4[8], b4[4];
#pragma unroll
        for (int i = 0; i < 8; ++i) a4[i] = *(const float4*)&sin_[(rowg * 8 + i) * 68 + k];
#pragma unroll
        for (int kk = 0; kk < 4; ++kk) b4[kk] = *(const float4*)&sw[(k + kk) * 128 + colg * 4];
#pragma unroll
        for (int i = 0; i < 8; ++i) {
#pragma unroll
            for (int kk = 0; kk < 4; ++kk) {
                float av = (kk == 0) ? a4[i].x : (kk == 1) ? a4[i].y : (kk == 2) ? a4[i].z : a4[i].w;
                acc[i].x += av * b4[kk].x;
                acc[i].y += av * b4[kk].y;
                acc[i].z += av * b4[kk].z;
                acc[i].w += av * b4[kk].w;
            }
        }
    }
#pragma unroll
    for (int i = 0; i < 8; ++i) {
        f16x4 h;
        h[0] = (_Float16)acc[i].x; h[1] = (_Float16)acc[i].y;
        h[2] = (_Float16)acc[i].z; h[3] = (_Float16)acc[i].w;
        *(f16x4*)&Pp[(size_t)(row0 + rowg * 8 + i) * 128 + colg * 4] = h;
    }
}

// ---------------------------------------------------------------------------
// Kernel 2b: Q' + anchors. (unchanged — verified; stride-128 store restored)
// ---------------------------------------------------------------------------
__global__ __launch_bounds__(256) void k_qp(const float* __restrict__ xyzs,
                                            const float* __restrict__ feats,
                                            const float* __restrict__ w1,
                                            const float* __restrict__ b1,
                                            const int* __restrict__ fps_idx,
                                            float* __restrict__ Qp,
                                            float* __restrict__ out_anchor) {
    __shared__ float sw[68 * 128];
    __shared__ float sin_[64 * 68];
    __shared__ float sb[128];
    int tid = threadIdx.x;
    for (int i = tid; i < 68 * 128; i += 256) {
        int r = i >> 7, c = i & 127;
        float v = 0.f;
        if (r < 64) v = w1[(64 + r) * 128 + c];
        else if (r < 67) v = w1[(128 + r - 64) * 128 + c];
        sw[i] = v;
    }
    if (tid < 128) sb[tid] = b1[tid];
    int row0 = blockIdx.x * 64;
    int bt = row0 >> 9;
    size_t fbase = (size_t)bt * NN;
    {
        int r = tid >> 2, seg = tid & 3;
        int aidx = fps_idx[row0 + r];
        const float4* fr = (const float4*)(feats + (fbase + aidx) * CC);
#pragma unroll
        for (int i = 0; i < 4; ++i) {
            float4 v = fr[seg * 4 + i];
            *(float4*)&sin_[r * 68 + seg * 16 + i * 4] = v;
        }
    }
    if (tid < 64) {
        int aidx = fps_idx[row0 + tid];
        const float* xs = xyzs + (fbase + aidx) * 3;
        float x = xs[0], y = xs[1], z = xs[2];
        sin_[tid * 68 + 64] = -x;
        sin_[tid * 68 + 65] = -y;
        sin_[tid * 68 + 66] = -z;
        sin_[tid * 68 + 67] = 0.f;
        out_anchor[(size_t)(row0 + tid) * 3 + 0] = x;
        out_anchor[(size_t)(row0 + tid) * 3 + 1] = y;
        out_anchor[(size_t)(row0 + tid) * 3 + 2] = z;
    }
    __syncthreads();

    int rowg = tid >> 5, colg = tid & 31;
    float4 bias = *(const float4*)&sb[colg * 4];
    float4 acc[8];
#pragma unroll
    for (int i = 0; i < 8; ++i) acc[i] = bias;
    for (int k = 0; k < 68; k += 4) {
        float4 a4[8], b4[4];
#pragma unroll
        for (int i = 0; i < 8; ++i) a4[i] = *(const float4*)&sin_[(rowg * 8 + i) * 68 + k];
#pragma unroll
        for (int kk = 0; kk < 4; ++kk) b4[kk] = *(const float4*)&sw[(k + kk) * 128 + colg * 4];
#pragma unroll
        for (int i = 0; i < 8; ++i) {
#pragma unroll
            for (int kk = 0; kk < 4; ++kk) {
                float av = (kk == 0) ? a4[i].x : (kk == 1) ? a4[i].y : (kk == 2) ? a4[i].z : a4[i].w;
                acc[i].x += av * b4[kk].x;
                acc[i].y += av * b4[kk].y;
                acc[i].z += av * b4[kk].z;
                acc[i].w += av * b4[kk].w;
            }
        }
    }
#pragma unroll
    for (int i = 0; i < 8; ++i)
        *(float4*)&Qp[(size_t)(row0 + rowg * 8 + i) * 128 + colg * 4] = acc[i];
}

// ---------------------------------------------------------------------------
// Kernel 3: exact stable top-K=32 nearest + radius filter.
// Packed u64 key DPP min-reduce; SALU-assisted invalidation; grouped rescan.
// Extraction order/ties bit-identical to rounds 4/5.
// ---------------------------------------------------------------------------
__global__ __launch_bounds__(256) void k_knn(const float* __restrict__ xyzs,
                                             const float* __restrict__ anchors,
                                             int* __restrict__ idxk) {
    __shared__ float sx[NN], sy[NN], sz[NN];
    int tid = threadIdx.x;
    int wave = tid >> 6, lane = tid & 63;
    int bt = blockIdx.x >> 6;              // 64 blocks per (b,t)
    int sub = blockIdx.x & 63;
    int b = bt >> 3, t = bt & 7;
    int tn = (t + 1 < TT) ? (t + 1) : (TT - 1);
    const float* src = xyzs + ((size_t)(b * TT + tn)) * NN * 3;
    for (int i = tid; i < NN; i += 256) {
        sx[i] = src[i * 3 + 0];
        sy[i] = src[i * 3 + 1];
        sz[i] = src[i * 3 + 2];
    }
    __syncthreads();

    for (int a = 0; a < 2; ++a) {
        int mrow = bt * MM + sub * 8 + wave * 2 + a;
        float ax = anchors[mrow * 3 + 0];
        float ay = anchors[mrow * 3 + 1];
        float az = anchors[mrow * 3 + 2];
        float d[32];
#pragma unroll
        for (int j = 0; j < 32; ++j) {
            int p = j * 64 + lane;
            float dx = sx[p] - ax, dy = sy[p] - ay, dz = sz[p] - az;
            d[j] = dx * dx + dy * dy + dz * dz;
        }
        int p0 = 0;
        int myidx = 0;
        for (int r = 0; r < KK; ++r) {
            // lane min over 32 via 4 serial groups of 8 + 3-node tree
            float gd[4];
            int gp[4];
#pragma unroll
            for (int g = 0; g < 4; ++g) {
                gd[g] = d[g * 8];
                gp[g] = (g * 8) * 64 + lane;
#pragma unroll
                for (int jj = 1; jj < 8; ++jj) {
                    float dj = d[g * 8 + jj];
                    if (dj < gd[g]) { gd[g] = dj; gp[g] = (g * 8 + jj) * 64 + lane; }  // strict <
                }
            }
            bool u01 = gd[1] < gd[0], u23 = gd[3] < gd[2];
            float da = u01 ? gd[1] : gd[0], db = u23 ? gd[3] : gd[2];
            int pa = u01 ? gp[1] : gp[0], pb = u23 ? gp[3] : gp[2];
            bool uf = db < da;
            float bd = uf ? db : da;
            int bp = uf ? pb : pa;
            // global min via packed key (min d, tie -> min p)
            unsigned long long key =
                ((unsigned long long)(unsigned)__builtin_bit_cast(unsigned, bd) << 32) |
                (unsigned)bp;
            unsigned long long wkey = wave_minkey(key);
            int pstar = (int)(unsigned)wkey;
            float dstar = __builtin_bit_cast(float, (unsigned)(wkey >> 32));
            if (r == 0) { p0 = pstar; myidx = pstar; }
            int outp = (dstar <= RAD2) ? pstar : p0;   // radius replacement
            if (lane == r) myidx = outp;
            if (r < KK - 1) {
                int lanew = pstar & 63;                 // uniform (SGPR)
                int jw = pstar >> 6;                    // uniform (SGPR)
                bool imw = (lane == lanew);
#pragma unroll
                for (int j = 0; j < 32; ++j)
                    d[j] = (imw && j == jw) ? FINF : d[j];
            }
        }
        if (lane < KK) idxk[(size_t)mrow * KK + lane] = myidx;
    }
}

// ---------------------------------------------------------------------------
// Kernel 4: persistent-block fp16 MFMA MLP (layers 2+3) + max over K.
// (unchanged — verified; 512 thr / 8 waves)
// ---------------------------------------------------------------------------
#define SM_W2 0
#define SM_W3 32768
#define SM_H1 98304
#define SM_H2 114688
#define SM_B2 131072
#define SM_B3 131584
#define SM_TOTAL 132608

__global__ __launch_bounds__(512, 1) void k_mlp(const _Float16* __restrict__ Pp,
                                                const float* __restrict__ Qp,
                                                const int* __restrict__ idxk,
                                                const float* __restrict__ w2,
                                                const float* __restrict__ b2,
                                                const float* __restrict__ w3,
                                                const float* __restrict__ b3,
                                                float* __restrict__ out_feat) {
    extern __shared__ char smem[];
    int tid = threadIdx.x;
    int bid = blockIdx.x;                  // 0..255

    for (int i = tid; i < 128 * 128; i += 512) {
        int n = i & 127, kk = i >> 7;
        _Float16 v = (_Float16)w2[kk * 128 + n];
        *(_Float16*)(smem + SM_W2 + n * 256 + ((2 * kk) ^ ((n & 7) << 4))) = v;
    }
    for (int i = tid; i < 256 * 128; i += 512) {
        int n = i & 255, kk = i >> 8;
        _Float16 v = (_Float16)w3[kk * 256 + n];
        *(_Float16*)(smem + SM_W3 + n * 256 + ((2 * kk) ^ ((n & 7) << 4))) = v;
    }
    if (tid < 128) *(float*)(smem + SM_B2 + tid * 4) = b2[tid];
    if (tid < 256) *(float*)(smem + SM_B3 + tid * 4) = b3[tid];
    __syncthreads();

    int lane = tid & 63;
    int w = tid >> 6;                      // 0..7
    int wm = w >> 2, wn = w & 3;           // 2 anchors x 4 col-groups
    int l15 = lane & 15, g = lane >> 4;
    int hswz = (l15 & 7) << 4;

    const f32x4 zero4 = {0.f, 0.f, 0.f, 0.f};

    for (int c = 0; c < 32; ++c) {
        int a0 = bid * 64 + c * 2;
        int bt = a0 >> 9;

        {
            int r = tid >> 3, seg = tid & 7;
            int arow = a0 + (r >> 5);
            int kidx = r & 31;
            int nk = idxk[(size_t)arow * KK + kidx];
            const _Float16* ps = Pp + ((size_t)(bt * NN + nk)) * 128 + seg * 16;
            const float* qs = Qp + (size_t)arow * 128 + seg * 16;
            int rowbase = SM_H1 + r * 256;
            int swz = (r & 7) << 4;
#pragma unroll
            for (int i = 0; i < 2; ++i) {
                f16x8 pv = *(const f16x8*)(ps + i * 8);
                f32x4 q0 = *(const f32x4*)(qs + i * 8);
                f32x4 q1 = *(const f32x4*)(qs + i * 8 + 4);
                f16x8 hv;
#pragma unroll
                for (int j = 0; j < 4; ++j) hv[j] = (_Float16)fmaxf((float)pv[j] + q0[j], 0.f);
#pragma unroll
                for (int j = 0; j < 4; ++j) hv[4 + j] = (_Float16)fmaxf((float)pv[4 + j] + q1[j], 0.f);
                *(f16x8*)(smem + rowbase + ((seg * 32 + i * 16) ^ swz)) = hv;
            }
        }
        __syncthreads();

        f32x4 acc2[2][2];
#pragma unroll
        for (int m = 0; m < 2; ++m)
#pragma unroll
            for (int n = 0; n < 2; ++n) acc2[m][n] = zero4;

#pragma unroll
        for (int ks = 0; ks < 4; ++ks) {
            int kbyte = ks * 64 + g * 16;
            f16x8 af[2], bf[2];
#pragma unroll
            for (int m = 0; m < 2; ++m) {
                int row = wm * 32 + m * 16 + l15;
                af[m] = *(const f16x8*)(smem + SM_H1 + row * 256 + (kbyte ^ hswz));
            }
#pragma unroll
            for (int n = 0; n < 2; ++n) {
                int col = wn * 32 + n * 16 + l15;
                bf[n] = *(const f16x8*)(smem + SM_W2 + col * 256 + (kbyte ^ hswz));
            }
#pragma unroll
            for (int m = 0; m < 2; ++m)
#pragma unroll
                for (int n = 0; n < 2; ++n)
                    acc2[m][n] = __builtin_amdgcn_mfma_f32_16x16x32_f16(af[m], bf[n], acc2[m][n], 0, 0, 0);
        }
#pragma unroll
        for (int m = 0; m < 2; ++m)
#pragma unroll
            for (int n = 0; n < 2; ++n) {
                int col = wn * 32 + n * 16 + l15;
                float bb = *(const float*)(smem + SM_B2 + col * 4);
#pragma unroll
                for (int r = 0; r < 4; ++r) {
                    int row = wm * 32 + m * 16 + g * 4 + r;
                    float v = fmaxf(acc2[m][n][r] + bb, 0.f);
                    *(_Float16*)(smem + SM_H2 + row * 256 + ((2 * col) ^ ((row & 7) << 4))) = (_Float16)v;
                }
            }
        __syncthreads();

        f32x4 acc3[2][4];
#pragma unroll
        for (int m = 0; m < 2; ++m)
#pragma unroll
            for (int n = 0; n < 4; ++n) acc3[m][n] = zero4;

#pragma unroll
        for (int ks = 0; ks < 4; ++ks) {
            int kbyte = ks * 64 + g * 16;
            f16x8 af[2], bf[4];
#pragma unroll
            for (int m = 0; m < 2; ++m) {
                int row = wm * 32 + m * 16 + l15;
                af[m] = *(const f16x8*)(smem + SM_H2 + row * 256 + (kbyte ^ hswz));
            }
#pragma unroll
            for (int n = 0; n < 4; ++n) {
                int col = wn * 64 + n * 16 + l15;
                bf[n] = *(const f16x8*)(smem + SM_W3 + col * 256 + (kbyte ^ hswz));
            }
#pragma unroll
            for (int m = 0; m < 2; ++m)
#pragma unroll
                for (int n = 0; n < 4; ++n)
                    acc3[m][n] = __builtin_amdgcn_mfma_f32_16x16x32_f16(af[m], bf[n], acc3[m][n], 0, 0, 0);
        }
#pragma unroll
        for (int n = 0; n < 4; ++n) {
            int col = wn * 64 + n * 16 + l15;
            float s = acc3[0][n][0];
#pragma unroll
            for (int r = 1; r < 4; ++r) s = fmaxf(s, acc3[0][n][r]);
#pragma unroll
            for (int r = 0; r < 4; ++r) s = fmaxf(s, acc3[1][n][r]);
            s = fmaxf(s, __shfl_xor(s, 16));
            s = fmaxf(s, __shfl_xor(s, 32));
            if (g == 0) {
                float bb = *(const float*)(smem + SM_B3 + col * 4);
                out_feat[(size_t)(a0 + wm) * H3DIM + col] = fmaxf(s + bb, 0.f);
            }
        }
        __syncthreads();
    }
}

// ---------------------------------------------------------------------------
extern "C" void kernel_launch(void* const* d_in, const int* in_sizes, int n_in,
                              void* d_out, int out_size, void* d_ws, size_t ws_size,
                              hipStream_t stream) {
    const float* xyzs  = (const float*)d_in[0];
    const float* feats = (const float*)d_in[1];
    const float* w1 = (const float*)d_in[2];
    const float* b1 = (const float*)d_in[3];
    const float* w2 = (const float*)d_in[4];
    const float* b2 = (const float*)d_in[5];
    const float* w3 = (const float*)d_in[6];
    const float* b3 = (const float*)d_in[7];

    float* out_anchor = (float*)d_out;
    float* out_feat = out_anchor + (size_t)BB * TT * MM * 3;

    char* ws = (char*)d_ws;
    int* fps_idx = (int*)ws;                                   // 64 KB
    int* idxk = (int*)(ws + 65536);                            // 2 MB
    _Float16* Pp = (_Float16*)(ws + 65536 + 2097152);          // B*T*N*128 fp16 = 16 MB
    float* Qp = (float*)(ws + 65536 + 2097152 + 16777216);     // B*T*M*128 fp32 = 8 MB
    if (ws_size < (size_t)(65536 + 2097152 + 16777216) + (size_t)BB * TT * MM * 128 * 4)
        return;

    k_fps<<<BB * TT, 256, 0, stream>>>(xyzs, fps_idx);
    k_pp<<<BB * TT * NN / 64, 256, 0, stream>>>(xyzs, feats, w1, Pp);
    k_qp<<<BB * TT * MM / 64, 256, 0, stream>>>(xyzs, feats, w1, b1, fps_idx, Qp, out_anchor);
    k_knn<<<BB * TT * 64, 256, 0, stream>>>(xyzs, out_anchor, idxk);

    (void)hipFuncSetAttribute((const void*)k_mlp, hipFuncAttributeMaxDynamicSharedMemorySize, SM_TOTAL);
    k_mlp<<<256, 512, SM_TOTAL, stream>>>(Pp, Qp, idxk, w2, b2, w3, b3, out_feat);
}

// Round 9
// 622.075 us; speedup vs baseline: 1.0161x; 1.0161x over previous
//
#include <hip/hip_runtime.h>

// Problem constants (B=4, T=8, N=2048, C=64)
#define BB 4
#define TT 8
#define NN 2048
#define CC 64
#define MM 512           // N / SPATIAL_STRIDE
#define KK 32
#define H3DIM 256
#define RAD2 0.25f
#define FINF 3.4e38f

typedef _Float16 f16x8 __attribute__((ext_vector_type(8)));
typedef _Float16 f16x4 __attribute__((ext_vector_type(4)));
typedef float f32x4 __attribute__((ext_vector_type(4)));

// ---------------------------------------------------------------------------
// f32 DPP wave-64 max tree (row_shr 1/2/4/8 + row_bcast15/31, result lane 63).
// HW-validated rounds 2-5 (fast: 2 dependent VALU per level).
// ---------------------------------------------------------------------------
template <int CTRL>
__device__ __forceinline__ float dpp_max_step(float x) {
    int xi = __builtin_bit_cast(int, x);
    int yi = __builtin_amdgcn_update_dpp(xi, xi, CTRL, 0xf, 0xf, false);
    return fmaxf(x, __builtin_bit_cast(float, yi));
}
__device__ __forceinline__ float wave_max64(float x) {
    x = dpp_max_step<0x111>(x);
    x = dpp_max_step<0x112>(x);
    x = dpp_max_step<0x114>(x);
    x = dpp_max_step<0x118>(x);
    x = dpp_max_step<0x142>(x);
    x = dpp_max_step<0x143>(x);
    return __builtin_bit_cast(float, __builtin_amdgcn_readlane(__builtin_bit_cast(int, x), 63));
}
// Packed u64 DPP min (validated round 8 in k_knn).
template <int CTRL>
__device__ __forceinline__ unsigned long long dpp_minkey_step(unsigned long long k) {
    int lo = (int)(unsigned)k;
    int hi = (int)(unsigned)(k >> 32);
    int slo = __builtin_amdgcn_update_dpp(lo, lo, CTRL, 0xf, 0xf, false);
    int shi = __builtin_amdgcn_update_dpp(hi, hi, CTRL, 0xf, 0xf, false);
    unsigned long long s = ((unsigned long long)(unsigned)shi << 32) | (unsigned)slo;
    return s < k ? s : k;
}
__device__ __forceinline__ unsigned long long wave_minkey(unsigned long long k) {
    k = dpp_minkey_step<0x111>(k);
    k = dpp_minkey_step<0x112>(k);
    k = dpp_minkey_step<0x114>(k);
    k = dpp_minkey_step<0x118>(k);
    k = dpp_minkey_step<0x142>(k);
    k = dpp_minkey_step<0x143>(k);
    int lo = __builtin_amdgcn_readlane((int)(unsigned)k, 63);
    int hi = __builtin_amdgcn_readlane((int)(unsigned)(k >> 32), 63);
    return ((unsigned long long)(unsigned)hi << 32) | (unsigned)lo;
}

// ---------------------------------------------------------------------------
// Kernel 1: farthest point sampling. 4 waves (256 thr) per (b,t) cloud.
// Round-4 reduce core (f32 DPP + ballot + readlane) + winner-lane register
// coord select (3-level cndmask tree) -> LDS float4 record -> combine gives
// next cur coords directly (no second LDS round-trip).
// Tie-break smallest index, exact: lane-major ownership + strict-> trees.
// ---------------------------------------------------------------------------
__global__ __launch_bounds__(256) void k_fps(const float* __restrict__ xyzs,
                                             int* __restrict__ fps_idx) {
    int bt = blockIdx.x;
    int tid = threadIdx.x;
    int lane = tid & 63, w = tid >> 6;
    __shared__ float sx[NN], sy[NN], sz[NN];
    __shared__ float4 rec_xyzd[2][4];           // [buf][wave] = {x,y,z,d}
    __shared__ __align__(16) int rec_p[2][4];   // [buf][wave] = winner p
    const float* src = xyzs + (size_t)bt * NN * 3;
    for (int i = tid; i < NN; i += 256) {
        sx[i] = src[i * 3 + 0];
        sy[i] = src[i * 3 + 1];
        sz[i] = src[i * 3 + 2];
    }
    __syncthreads();

    float px[8], py[8], pz[8], dist[8];
#pragma unroll
    for (int j = 0; j < 8; ++j) {
        int p = tid * 8 + j;
        px[j] = sx[p]; py[j] = sy[p]; pz[j] = sz[p];
        dist[j] = 1e10f;
    }

    if (tid == 0) fps_idx[bt * MM + 0] = 0;
    int pbase = tid * 8;
    float cx = sx[0], cy = sy[0], cz = sz[0];

    for (int it = 1; it < MM; ++it) {
        // distance update (exact expression from rounds 1-8)
        float nd[8];
#pragma unroll
        for (int j = 0; j < 8; ++j) {
            float dx = px[j] - cx, dy = py[j] - cy, dz = pz[j] - cz;
            float d = dx * dx + dy * dy + dz * dz;
            nd[j] = fminf(dist[j], d);
            dist[j] = nd[j];
        }
        // lane argmax: 2 groups of 4 (strict > keeps smallest j) + tree
        float gd0 = nd[0]; int gj0 = 0;
#pragma unroll
        for (int j = 1; j < 4; ++j) if (nd[j] > gd0) { gd0 = nd[j]; gj0 = j; }
        float gd1 = nd[4]; int gj1 = 4;
#pragma unroll
        for (int j = 5; j < 8; ++j) if (nd[j] > gd1) { gd1 = nd[j]; gj1 = j; }
        bool gt = gd1 > gd0;                 // strict: group0 wins ties (smaller j)
        float bestd = gt ? gd1 : gd0;
        int bestj = gt ? gj1 : gj0;
        int bestp = pbase + bestj;
        // wave argmax (round-4 validated): f32 DPP max + ballot lowest lane
        float wmax = wave_max64(bestd);
        unsigned long long mask = __ballot(bestd == wmax);
        int wl = __ffsll(mask) - 1;
        int wbp = __builtin_amdgcn_readlane(bestp, wl);
        if (lane == wl) {                    // winner lane: coords from registers
            bool b0 = (bestj & 1) != 0, b1 = (bestj & 2) != 0, b2 = (bestj & 4) != 0;
            float x01 = b0 ? px[1] : px[0], x23 = b0 ? px[3] : px[2];
            float x45 = b0 ? px[5] : px[4], x67 = b0 ? px[7] : px[6];
            float y01 = b0 ? py[1] : py[0], y23 = b0 ? py[3] : py[2];
            float y45 = b0 ? py[5] : py[4], y67 = b0 ? py[7] : py[6];
            float z01 = b0 ? pz[1] : pz[0], z23 = b0 ? pz[3] : pz[2];
            float z45 = b0 ? pz[5] : pz[4], z67 = b0 ? pz[7] : pz[6];
            float x0123 = b1 ? x23 : x01, x4567 = b1 ? x67 : x45;
            float y0123 = b1 ? y23 : y01, y4567 = b1 ? y67 : y45;
            float z0123 = b1 ? z23 : z01, z4567 = b1 ? z67 : z45;
            float4 r;
            r.x = b2 ? x4567 : x0123;
            r.y = b2 ? y4567 : y0123;
            r.z = b2 ? z4567 : z0123;
            r.w = wmax;
            rec_xyzd[it & 1][w] = r;
        }
        if (lane == 0) rec_p[it & 1][w] = wbp;
        __syncthreads();
        // combine 4 wave records: vector loads + 3-node f32 tree
        float4 r0 = rec_xyzd[it & 1][0];
        float4 r1 = rec_xyzd[it & 1][1];
        float4 r2 = rec_xyzd[it & 1][2];
        float4 r3 = rec_xyzd[it & 1][3];
        int4 pv = *(const int4*)&rec_p[it & 1][0];
        bool t01 = r1.w > r0.w, t23 = r3.w > r2.w;   // strict: earlier wave = smaller p
        float4 ra = t01 ? r1 : r0; int pa = t01 ? pv.y : pv.x;
        float4 rb = t23 ? r3 : r2; int pb = t23 ? pv.w : pv.z;
        bool tf = rb.w > ra.w;
        float4 rf = tf ? rb : ra;
        int pf = tf ? pb : pa;
        cx = rf.x; cy = rf.y; cz = rf.z;
        if (tid == 0) fps_idx[bt * MM + it] = pf;
    }
}

// ---------------------------------------------------------------------------
// Kernel 2a: P'[row,c] (fp16) = feat_n.W1[0:64] + xyz_n.W1[128:131]
// (unchanged — verified)
// ---------------------------------------------------------------------------
__global__ __launch_bounds__(256) void k_pp(const float* __restrict__ xyzs,
                                            const float* __restrict__ feats,
                                            const float* __restrict__ w1,
                                            _Float16* __restrict__ Pp) {
    __shared__ float sw[68 * 128];
    __shared__ float sin_[64 * 68];
    int tid = threadIdx.x;
    for (int i = tid; i < 68 * 128; i += 256) {
        int r = i >> 7, c = i & 127;
        float v = 0.f;
        if (r < 64) v = w1[r * 128 + c];
        else if (r < 67) v = w1[(128 + r - 64) * 128 + c];
        sw[i] = v;
    }
    int row0 = blockIdx.x * 64;
    int bt = row0 >> 11;
    int b = bt >> 3, t = bt & 7;
    int tn = (t + 1 < TT) ? (t + 1) : (TT - 1);
    size_t nbase = (size_t)(b * TT + tn) * NN + (row0 & (NN - 1));
    const float* fsrc = feats + nbase * CC;
    const float* xsrc = xyzs + nbase * 3;
    for (int i = tid; i < 1024; i += 256) {
        float4 v = ((const float4*)fsrc)[i];
        int r = i >> 4, c = (i & 15) * 4;
        *(float4*)&sin_[r * 68 + c] = v;
    }
    if (tid < 192) {
        int r = tid / 3, c = tid - r * 3;
        sin_[r * 68 + 64 + c] = xsrc[tid];
    }
    if (tid < 64) sin_[tid * 68 + 67] = 0.f;
    __syncthreads();

    int rowg = tid >> 5, colg = tid & 31;
    float4 acc[8];
#pragma unroll
    for (int i = 0; i < 8; ++i) acc[i] = make_float4(0.f, 0.f, 0.f, 0.f);
    for (int k = 0; k < 68; k += 4) {
        float4 a4[8], b4[4];
#pragma unroll
        for (int i = 0; i < 8; ++i) a4[i] = *(const float4*)&sin_[(rowg * 8 + i) * 68 + k];
#pragma unroll
        for (int kk = 0; kk < 4; ++kk) b4[kk] = *(const float4*)&sw[(k + kk) * 128 + colg * 4];
#pragma unroll
        for (int i = 0; i < 8; ++i) {
#pragma unroll
            for (int kk = 0; kk < 4; ++kk) {
                float av = (kk == 0) ? a4[i].x : (kk == 1) ? a4[i].y : (kk == 2) ? a4[i].z : a4[i].w;
                acc[i].x += av * b4[kk].x;
                acc[i].y += av * b4[kk].y;
                acc[i].z += av * b4[kk].z;
                acc[i].w += av * b4[kk].w;
            }
        }
    }
#pragma unroll
    for (int i = 0; i < 8; ++i) {
        f16x4 h;
        h[0] = (_Float16)acc[i].x; h[1] = (_Float16)acc[i].y;
        h[2] = (_Float16)acc[i].z; h[3] = (_Float16)acc[i].w;
        *(f16x4*)&Pp[(size_t)(row0 + rowg * 8 + i) * 128 + colg * 4] = h;
    }
}

// ---------------------------------------------------------------------------
// Kernel 2b: Q' + anchors. (unchanged — verified)
// ---------------------------------------------------------------------------
__global__ __launch_bounds__(256) void k_qp(const float* __restrict__ xyzs,
                                            const float* __restrict__ feats,
                                            const float* __restrict__ w1,
                                            const float* __restrict__ b1,
                                            const int* __restrict__ fps_idx,
                                            float* __restrict__ Qp,
                                            float* __restrict__ out_anchor) {
    __shared__ float sw[68 * 128];
    __shared__ float sin_[64 * 68];
    __shared__ float sb[128];
    int tid = threadIdx.x;
    for (int i = tid; i < 68 * 128; i += 256) {
        int r = i >> 7, c = i & 127;
        float v = 0.f;
        if (r < 64) v = w1[(64 + r) * 128 + c];
        else if (r < 67) v = w1[(128 + r - 64) * 128 + c];
        sw[i] = v;
    }
    if (tid < 128) sb[tid] = b1[tid];
    int row0 = blockIdx.x * 64;
    int bt = row0 >> 9;
    size_t fbase = (size_t)bt * NN;
    {
        int r = tid >> 2, seg = tid & 3;
        int aidx = fps_idx[row0 + r];
        const float4* fr = (const float4*)(feats + (fbase + aidx) * CC);
#pragma unroll
        for (int i = 0; i < 4; ++i) {
            float4 v = fr[seg * 4 + i];
            *(float4*)&sin_[r * 68 + seg * 16 + i * 4] = v;
        }
    }
    if (tid < 64) {
        int aidx = fps_idx[row0 + tid];
        const float* xs = xyzs + (fbase + aidx) * 3;
        float x = xs[0], y = xs[1], z = xs[2];
        sin_[tid * 68 + 64] = -x;
        sin_[tid * 68 + 65] = -y;
        sin_[tid * 68 + 66] = -z;
        sin_[tid * 68 + 67] = 0.f;
        out_anchor[(size_t)(row0 + tid) * 3 + 0] = x;
        out_anchor[(size_t)(row0 + tid) * 3 + 1] = y;
        out_anchor[(size_t)(row0 + tid) * 3 + 2] = z;
    }
    __syncthreads();

    int rowg = tid >> 5, colg = tid & 31;
    float4 bias = *(const float4*)&sb[colg * 4];
    float4 acc[8];
#pragma unroll
    for (int i = 0; i < 8; ++i) acc[i] = bias;
    for (int k = 0; k < 68; k += 4) {
        float4 a4[8], b4[4];
#pragma unroll
        for (int i = 0; i < 8; ++i) a4[i] = *(const float4*)&sin_[(rowg * 8 + i) * 68 + k];
#pragma unroll
        for (int kk = 0; kk < 4; ++kk) b4[kk] = *(const float4*)&sw[(k + kk) * 128 + colg * 4];
#pragma unroll
        for (int i = 0; i < 8; ++i) {
#pragma unroll
            for (int kk = 0; kk < 4; ++kk) {
                float av = (kk == 0) ? a4[i].x : (kk == 1) ? a4[i].y : (kk == 2) ? a4[i].z : a4[i].w;
                acc[i].x += av * b4[kk].x;
                acc[i].y += av * b4[kk].y;
                acc[i].z += av * b4[kk].z;
                acc[i].w += av * b4[kk].w;
            }
        }
    }
#pragma unroll
    for (int i = 0; i < 8; ++i)
        *(float4*)&Qp[(size_t)(row0 + rowg * 8 + i) * 128 + colg * 4] = acc[i];
}

// ---------------------------------------------------------------------------
// Kernel 3: exact stable top-K=32 nearest + radius filter.
// (unchanged from round 8 — verified)
// ---------------------------------------------------------------------------
__global__ __launch_bounds__(256) void k_knn(const float* __restrict__ xyzs,
                                             const float* __restrict__ anchors,
                                             int* __restrict__ idxk) {
    __shared__ float sx[NN], sy[NN], sz[NN];
    int tid = threadIdx.x;
    int wave = tid >> 6, lane = tid & 63;
    int bt = blockIdx.x >> 6;              // 64 blocks per (b,t)
    int sub = blockIdx.x & 63;
    int b = bt >> 3, t = bt & 7;
    int tn = (t + 1 < TT) ? (t + 1) : (TT - 1);
    const float* src = xyzs + ((size_t)(b * TT + tn)) * NN * 3;
    for (int i = tid; i < NN; i += 256) {
        sx[i] = src[i * 3 + 0];
        sy[i] = src[i * 3 + 1];
        sz[i] = src[i * 3 + 2];
    }
    __syncthreads();

    for (int a = 0; a < 2; ++a) {
        int mrow = bt * MM + sub * 8 + wave * 2 + a;
        float ax = anchors[mrow * 3 + 0];
        float ay = anchors[mrow * 3 + 1];
        float az = anchors[mrow * 3 + 2];
        float d[32];
#pragma unroll
        for (int j = 0; j < 32; ++j) {
            int p = j * 64 + lane;
            float dx = sx[p] - ax, dy = sy[p] - ay, dz = sz[p] - az;
            d[j] = dx * dx + dy * dy + dz * dz;
        }
        int p0 = 0;
        int myidx = 0;
        for (int r = 0; r < KK; ++r) {
            // lane min over 32 via 4 serial groups of 8 + 3-node tree
            float gd[4];
            int gp[4];
#pragma unroll
            for (int g = 0; g < 4; ++g) {
                gd[g] = d[g * 8];
                gp[g] = (g * 8) * 64 + lane;
#pragma unroll
                for (int jj = 1; jj < 8; ++jj) {
                    float dj = d[g * 8 + jj];
                    if (dj < gd[g]) { gd[g] = dj; gp[g] = (g * 8 + jj) * 64 + lane; }  // strict <
                }
            }
            bool u01 = gd[1] < gd[0], u23 = gd[3] < gd[2];
            float da = u01 ? gd[1] : gd[0], db = u23 ? gd[3] : gd[2];
            int pa = u01 ? gp[1] : gp[0], pb = u23 ? gp[3] : gp[2];
            bool uf = db < da;
            float bd = uf ? db : da;
            int bp = uf ? pb : pa;
            // global min via packed key (min d, tie -> min p)
            unsigned long long key =
                ((unsigned long long)(unsigned)__builtin_bit_cast(unsigned, bd) << 32) |
                (unsigned)bp;
            unsigned long long wkey = wave_minkey(key);
            int pstar = (int)(unsigned)wkey;
            float dstar = __builtin_bit_cast(float, (unsigned)(wkey >> 32));
            if (r == 0) { p0 = pstar; myidx = pstar; }
            int outp = (dstar <= RAD2) ? pstar : p0;   // radius replacement
            if (lane == r) myidx = outp;
            if (r < KK - 1) {
                int lanew = pstar & 63;                 // uniform (SGPR)
                int jw = pstar >> 6;                    // uniform (SGPR)
                bool imw = (lane == lanew);
#pragma unroll
                for (int j = 0; j < 32; ++j)
                    d[j] = (imw && j == jw) ? FINF : d[j];
            }
        }
        if (lane < KK) idxk[(size_t)mrow * KK + lane] = myidx;
    }
}

// ---------------------------------------------------------------------------
// Kernel 4: persistent-block fp16 MFMA MLP (layers 2+3) + max over K.
// (unchanged — verified; 512 thr / 8 waves)
// ---------------------------------------------------------------------------
#define SM_W2 0
#define SM_W3 32768
#define SM_H1 98304
#define SM_H2 114688
#define SM_B2 131072
#define SM_B3 131584
#define SM_TOTAL 132608

__global__ __launch_bounds__(512, 1) void k_mlp(const _Float16* __restrict__ Pp,
                                                const float* __restrict__ Qp,
                                                const int* __restrict__ idxk,
                                                const float* __restrict__ w2,
                                                const float* __restrict__ b2,
                                                const float* __restrict__ w3,
                                                const float* __restrict__ b3,
                                                float* __restrict__ out_feat) {
    extern __shared__ char smem[];
    int tid = threadIdx.x;
    int bid = blockIdx.x;                  // 0..255

    for (int i = tid; i < 128 * 128; i += 512) {
        int n = i & 127, kk = i >> 7;
        _Float16 v = (_Float16)w2[kk * 128 + n];
        *(_Float16*)(smem + SM_W2 + n * 256 + ((2 * kk) ^ ((n & 7) << 4))) = v;
    }
    for (int i = tid; i < 256 * 128; i += 512) {
        int n = i & 255, kk = i >> 8;
        _Float16 v = (_Float16)w3[kk * 256 + n];
        *(_Float16*)(smem + SM_W3 + n * 256 + ((2 * kk) ^ ((n & 7) << 4))) = v;
    }
    if (tid < 128) *(float*)(smem + SM_B2 + tid * 4) = b2[tid];
    if (tid < 256) *(float*)(smem + SM_B3 + tid * 4) = b3[tid];
    __syncthreads();

    int lane = tid & 63;
    int w = tid >> 6;                      // 0..7
    int wm = w >> 2, wn = w & 3;           // 2 anchors x 4 col-groups
    int l15 = lane & 15, g = lane >> 4;
    int hswz = (l15 & 7) << 4;

    const f32x4 zero4 = {0.f, 0.f, 0.f, 0.f};

    for (int c = 0; c < 32; ++c) {
        int a0 = bid * 64 + c * 2;
        int bt = a0 >> 9;

        {
            int r = tid >> 3, seg = tid & 7;
            int arow = a0 + (r >> 5);
            int kidx = r & 31;
            int nk = idxk[(size_t)arow * KK + kidx];
            const _Float16* ps = Pp + ((size_t)(bt * NN + nk)) * 128 + seg * 16;
            const float* qs = Qp + (size_t)arow * 128 + seg * 16;
            int rowbase = SM_H1 + r * 256;
            int swz = (r & 7) << 4;
#pragma unroll
            for (int i = 0; i < 2; ++i) {
                f16x8 pv = *(const f16x8*)(ps + i * 8);
                f32x4 q0 = *(const f32x4*)(qs + i * 8);
                f32x4 q1 = *(const f32x4*)(qs + i * 8 + 4);
                f16x8 hv;
#pragma unroll
                for (int j = 0; j < 4; ++j) hv[j] = (_Float16)fmaxf((float)pv[j] + q0[j], 0.f);
#pragma unroll
                for (int j = 0; j < 4; ++j) hv[4 + j] = (_Float16)fmaxf((float)pv[4 + j] + q1[j], 0.f);
                *(f16x8*)(smem + rowbase + ((seg * 32 + i * 16) ^ swz)) = hv;
            }
        }
        __syncthreads();

        f32x4 acc2[2][2];
#pragma unroll
        for (int m = 0; m < 2; ++m)
#pragma unroll
            for (int n = 0; n < 2; ++n) acc2[m][n] = zero4;

#pragma unroll
        for (int ks = 0; ks < 4; ++ks) {
            int kbyte = ks * 64 + g * 16;
            f16x8 af[2], bf[2];
#pragma unroll
            for (int m = 0; m < 2; ++m) {
                int row = wm * 32 + m * 16 + l15;
                af[m] = *(const f16x8*)(smem + SM_H1 + row * 256 + (kbyte ^ hswz));
            }
#pragma unroll
            for (int n = 0; n < 2; ++n) {
                int col = wn * 32 + n * 16 + l15;
                bf[n] = *(const f16x8*)(smem + SM_W2 + col * 256 + (kbyte ^ hswz));
            }
#pragma unroll
            for (int m = 0; m < 2; ++m)
#pragma unroll
                for (int n = 0; n < 2; ++n)
                    acc2[m][n] = __builtin_amdgcn_mfma_f32_16x16x32_f16(af[m], bf[n], acc2[m][n], 0, 0, 0);
        }
#pragma unroll
        for (int m = 0; m < 2; ++m)
#pragma unroll
            for (int n = 0; n < 2; ++n) {
                int col = wn * 32 + n * 16 + l15;
                float bb = *(const float*)(smem + SM_B2 + col * 4);
#pragma unroll
                for (int r = 0; r < 4; ++r) {
                    int row = wm * 32 + m * 16 + g * 4 + r;
                    float v = fmaxf(acc2[m][n][r] + bb, 0.f);
                    *(_Float16*)(smem + SM_H2 + row * 256 + ((2 * col) ^ ((row & 7) << 4))) = (_Float16)v;
                }
            }
        __syncthreads();

        f32x4 acc3[2][4];
#pragma unroll
        for (int m = 0; m < 2; ++m)
#pragma unroll
            for (int n = 0; n < 4; ++n) acc3[m][n] = zero4;

#pragma unroll
        for (int ks = 0; ks < 4; ++ks) {
            int kbyte = ks * 64 + g * 16;
            f16x8 af[2], bf[4];
#pragma unroll
            for (int m = 0; m < 2; ++m) {
                int row = wm * 32 + m * 16 + l15;
                af[m] = *(const f16x8*)(smem + SM_H2 + row * 256 + (kbyte ^ hswz));
            }
#pragma unroll
            for (int n = 0; n < 4; ++n) {
                int col = wn * 64 + n * 16 + l15;
                bf[n] = *(const f16x8*)(smem + SM_W3 + col * 256 + (kbyte ^ hswz));
            }
#pragma unroll
            for (int m = 0; m < 2; ++m)
#pragma unroll
                for (int n = 0; n < 4; ++n)
                    acc3[m][n] = __builtin_amdgcn_mfma_f32_16x16x32_f16(af[m], bf[n], acc3[m][n], 0, 0, 0);
        }
#pragma unroll
        for (int n = 0; n < 4; ++n) {
            int col = wn * 64 + n * 16 + l15;
            float s = acc3[0][n][0];
#pragma unroll
            for (int r = 1; r < 4; ++r) s = fmaxf(s, acc3[0][n][r]);
#pragma unroll
            for (int r = 0; r < 4; ++r) s = fmaxf(s, acc3[1][n][r]);
            s = fmaxf(s, __shfl_xor(s, 16));
            s = fmaxf(s, __shfl_xor(s, 32));
            if (g == 0) {
                float bb = *(const float*)(smem + SM_B3 + col * 4);
                out_feat[(size_t)(a0 + wm) * H3DIM + col] = fmaxf(s + bb, 0.f);
            }
        }
        __syncthreads();
    }
}

// ---------------------------------------------------------------------------
extern "C" void kernel_launch(void* const* d_in, const int* in_sizes, int n_in,
                              void* d_out, int out_size, void* d_ws, size_t ws_size,
                              hipStream_t stream) {
    const float* xyzs  = (const float*)d_in[0];
    const float* feats = (const float*)d_in[1];
    const float* w1 = (const float*)d_in[2];
    const float* b1 = (const float*)d_in[3];
    const float* w2 = (const float*)d_in[4];
    const float* b2 = (const float*)d_in[5];
    const float* w3 = (const float*)d_in[6];
    const float* b3 = (const float*)d_in[7];

    float* out_anchor = (float*)d_out;
    float* out_feat = out_anchor + (size_t)BB * TT * MM * 3;

    char* ws = (char*)d_ws;
    int* fps_idx = (int*)ws;                                   // 64 KB
    int* idxk = (int*)(ws + 65536);                            // 2 MB
    _Float16* Pp = (_Float16*)(ws + 65536 + 2097152);          // B*T*N*128 fp16 = 16 MB
    float* Qp = (float*)(ws + 65536 + 2097152 + 16777216);     // B*T*M*128 fp32 = 8 MB
    if (ws_size < (size_t)(65536 + 2097152 + 16777216) + (size_t)BB * TT * MM * 128 * 4)
        return;

    k_fps<<<BB * TT, 256, 0, stream>>>(xyzs, fps_idx);
    k_pp<<<BB * TT * NN / 64, 256, 0, stream>>>(xyzs, feats, w1, Pp);
    k_qp<<<BB * TT * MM / 64, 256, 0, stream>>>(xyzs, feats, w1, b1, fps_idx, Qp, out_anchor);
    k_knn<<<BB * TT * 64, 256, 0, stream>>>(xyzs, out_anchor, idxk);

    (void)hipFuncSetAttribute((const void*)k_mlp, hipFuncAttributeMaxDynamicSharedMemorySize, SM_TOTAL);
    k_mlp<<<256, 512, SM_TOTAL, stream>>>(Pp, Qp, idxk, w2, b2, w3, b3, out_feat);
}